// Round 9
// baseline (123.209 us; speedup 1.0000x reference)
//
#include <hip/hip_runtime.h>
#include <hip/hip_bf16.h>
#include <math.h>

// PAM fused attention, round 9: 3-stage software pipeline
//   scores(i) || exp/pack/write(i-1) || PV(i-2)
// so the MFMA->exp result latency is covered by a full iteration, plus
// softmax-denominator l accumulated via MFMA (P x ones-B) on the idle matrix
// pipe instead of 16 VALU adds/tile. Layouts byte-identical to R7/R8
// (verified passing). B=4, Cm=6, C=64, N=4096.

#define BATCH 4
#define CMAP  6
#define CH    64
#define NSP   4096
#define TN    64        // keys per tile
#define NT    (NSP/TN)  // 64 tiles
#define PSTR  72        // p_scr row stride (bf16)

typedef __attribute__((ext_vector_type(8))) short short8;
typedef __attribute__((ext_vector_type(4))) float f32x4;

#if __has_builtin(__builtin_amdgcn_exp2f)
#define EXP2(x) __builtin_amdgcn_exp2f(x)
#else
#define EXP2(x) exp2f(x)
#endif

__device__ __forceinline__ unsigned f2bf(float f) {      // RNE f32->bf16 bits
    unsigned u = __float_as_uint(f);
    return (u + 0x7fffu + ((u >> 16) & 1u)) >> 16;
}

#define INVLN2 1.44269504088896f
#define SHIFT_BF16 0xC238u   /* bf16(-46.0): fixed softmax shift (exact, cancels) */
#define ONE_BF16   0x3F80u

// V fragment layout: featdf[b][ht(128)][cb(4)][512]
//   half-tile ht = 32 keys; cb = 16-channel block.
//   elem ((quad*16 + r)*8 + j) = V[m=ht*32+quad*8+j][ch=cb*16+r]
//   -> MFMA lane l=(quad*16+row16) loads its 16B at frag_base + l*8 elems.

// ---------------- kernel 1: projections + V fragment transpose ----------------
// grid (NSP/64, 2, BATCH), block 256. Each wave: 8 channels of the half.
__global__ void proj_kernel(const float* __restrict__ map1, const float* __restrict__ map2,
                            const float* __restrict__ fm,
                            const float* __restrict__ wb, const float* __restrict__ bb,
                            const float* __restrict__ wc, const float* __restrict__ bc,
                            const float* __restrict__ wd, const float* __restrict__ bd,
                            unsigned short* __restrict__ featq8,
                            unsigned short* __restrict__ featk8,
                            unsigned short* __restrict__ featdf)
{
    __shared__ unsigned short vfrag[2048];   // [ht(2)][cb_local(2)][512] = 4KB

    const int b    = blockIdx.z;
    const int half = blockIdx.y;
    const int lane = threadIdx.x & 63;
    const int og   = threadIdx.x >> 6;
    const int n    = blockIdx.x * 64 + lane;

    // ---- V projection: 8 channels per wave -> LDS in fragment order
    const int ht = lane >> 5;                 // half-tile within block
    const int mm = lane & 31;
    const int q4 = mm >> 3, jj = mm & 7;
    const int cb_local = og >> 1;
    float vals[CH];
#pragma unroll
    for (int c = 0; c < CH; ++c)
        vals[c] = fm[(size_t)(b*CH + c)*NSP + n];
#pragma unroll
    for (int oi = 0; oi < 8; ++oi) {
        const int o = half*32 + og*8 + oi;
        float a = bd[o];
#pragma unroll
        for (int c = 0; c < CH; ++c)
            a = fmaf(vals[c], wd[o*CH + c], a);
        const int r = (og & 1)*8 + oi;        // ch & 15
        vfrag[(ht*2 + cb_local)*512 + (q4*16 + r)*8 + jj] = (unsigned short)f2bf(a);
    }

    // ---- Q/K fragment rows (one wave per (x,b))
    if (half == 0 && og == 0) {
        float v1[CMAP], v2[CMAP];
#pragma unroll
        for (int c = 0; c < CMAP; ++c) {
            v1[c] = map1[(size_t)(b*CMAP + c)*NSP + n];
            v2[c] = map2[(size_t)(b*CMAP + c)*NSP + n];
        }
        unsigned qv[CMAP], kv[CMAP];
#pragma unroll
        for (int o = 0; o < CMAP; ++o) {
            float a1 = bb[o], a2 = bc[o];
#pragma unroll
            for (int c = 0; c < CMAP; ++c) {
                a1 = fmaf(v1[c], wb[o*CMAP + c], a1);
                a2 = fmaf(v2[c], wc[o*CMAP + c], a2);
            }
            qv[o] = f2bf(a1 * INVLN2);
            kv[o] = f2bf(a2);
        }
        uint4 qw, kw;
        qw.x = qv[0] | (qv[1] << 16);
        qw.y = qv[2] | (qv[3] << 16);
        qw.z = qv[4] | (qv[5] << 16);
        qw.w = SHIFT_BF16;                       // slot6 = -46, slot7 = 0
        kw.x = kv[0] | (kv[1] << 16);
        kw.y = kv[2] | (kv[3] << 16);
        kw.z = kv[4] | (kv[5] << 16);
        kw.w = ONE_BF16;                         // slot6 = 1, slot7 = 0
        *(uint4*)&featq8[(size_t)(b*NSP + n)*8] = qw;
        *(uint4*)&featk8[(size_t)(b*NSP + n)*8] = kw;
    }

    __syncthreads();

    // ---- fragment write-out: contiguous LDS read, coalesced global store
    {
        const int tt = threadIdx.x;
        const uint4 d = *(const uint4*)&vfrag[tt*8];
        const int ht2 = tt >> 7, inner = tt & 127;
        const size_t off = (((size_t)(b*128 + blockIdx.x*2 + ht2)*4) + half*2)*512
                         + (size_t)inner*8;
        *(uint4*)&featdf[off] = d;
    }
}

// ---------------- kernel 2: barrier-free attention, 3-stage pipeline ---------
// grid (NSP/64=64, 2, BATCH) = 512 blocks -> 2 blocks/CU, 8 waves/CU.
// Wave = 16 queries x 32 channels x 4096 keys. LDS ~18.5 KB/block.
__global__ __launch_bounds__(256, 2)
void attn_kernel(const unsigned short* __restrict__ featq8,
                 const unsigned short* __restrict__ featk8,
                 const unsigned short* __restrict__ featdf,
                 const float* __restrict__ fm, const float* __restrict__ alpha_p,
                 float* __restrict__ out)
{
    __shared__ unsigned short p_scr[2][4][16*PSTR];  // [buf][wave][q][m] wave-private

    const int b    = blockIdx.z;
    const int chh  = blockIdx.y;                   // 32-channel half
    const int t    = threadIdx.x;
    const int lane = t & 63, w = t >> 6;
    const int row16 = lane & 15, quad = lane >> 4;
    const int n0w  = blockIdx.x * 64 + w * 16;     // this wave's 16 queries

    // Q B-frag: B[k=quad*8+j][q=row16]; quads 1-3 zero (kills unguarded-K garbage)
    short8 qf = {0,0,0,0,0,0,0,0};
    if (quad == 0)
        qf = *(const short8*)&featq8[(size_t)(b*NSP + n0w + row16)*8];

    // ones B-frag for the l accumulator: D = P x 1 -> row sums of P,
    // D-layout q-mapping identical to acc0/acc1.
    const short8 onesb = {(short)ONE_BF16,(short)ONE_BF16,(short)ONE_BF16,(short)ONE_BF16,
                          (short)ONE_BF16,(short)ONE_BF16,(short)ONE_BF16,(short)ONE_BF16};

    // K A-frag stream: A[m][k'=quad*8+j]; quad>=1 reads neighbor rows (finite),
    // zeroed Q slots null those products.
    const unsigned short* kbase = featk8 + ((size_t)b*NSP + row16)*8 + quad*8;
    // V fragment stream: coalesced, lane*16B within each 1KB frag.
    const unsigned short* vfb = featdf + ((size_t)b*128*4)*512 + lane*8;
    const int cb0 = chh*2, cb1 = chh*2 + 1;

    const f32x4 zf = {0.f,0.f,0.f,0.f};
    f32x4 acc0 = zf, acc1 = zf, accL = zf;
    const int prow = row16 * PSTR;

    // exp -> pack bf16 (truncate) -> wave-private LDS write for one m-block.
    // C-layout: lane holds S^T[m = mb*16 + quad*4 + r][q = row16].
#define PAM_DO(pwp, mb, sv)                                                     \
    {                                                                           \
        const float p0 = EXP2(sv[0]), p1 = EXP2(sv[1]);                         \
        const float p2 = EXP2(sv[2]), p3 = EXP2(sv[3]);                         \
        uint2 pp;                                                               \
        pp.x = __builtin_amdgcn_perm(__float_as_uint(p1), __float_as_uint(p0), 0x07060302u); \
        pp.y = __builtin_amdgcn_perm(__float_as_uint(p3), __float_as_uint(p2), 0x07060302u); \
        *(uint2*)((pwp) + (mb)*16) = pp;                                        \
    }

#define LOADK(dst, mt)                                                          \
    dst##0 = *(const short8*)(kbase + ((mt)*TN +  0)*8);                        \
    dst##1 = *(const short8*)(kbase + ((mt)*TN + 16)*8);                        \
    dst##2 = *(const short8*)(kbase + ((mt)*TN + 32)*8);                        \
    dst##3 = *(const short8*)(kbase + ((mt)*TN + 48)*8);

#define LOADV(dst, vt)                                                          \
    dst##0 = *(const short8*)(vfb + (size_t)(((vt)*2 + 0)*4 + cb0)*512);        \
    dst##1 = *(const short8*)(vfb + (size_t)(((vt)*2 + 1)*4 + cb0)*512);        \
    dst##2 = *(const short8*)(vfb + (size_t)(((vt)*2 + 0)*4 + cb1)*512);        \
    dst##3 = *(const short8*)(vfb + (size_t)(((vt)*2 + 1)*4 + cb1)*512);

    short8 kc0, kc1, kc2, kc3, kn0, kn1, kn2, kn3;
    short8 vv0, vv1, vv2, vv3, vn0, vn1, vn2, vn3;
    f32x4 sp0, sp1, sp2, sp3;

    // ---------------- prologue ----------------
    LOADK(kc, 0)
    LOADV(vv, 0)            // V(0)
    LOADV(vn, 1)            // V(1)

    // i=0: scores(0) -> pack P(0) into buf[0]
    {
        f32x4 a0 = __builtin_amdgcn_mfma_f32_16x16x32_bf16(kc0, qf, zf, 0, 0, 0);
        f32x4 a1 = __builtin_amdgcn_mfma_f32_16x16x32_bf16(kc1, qf, zf, 0, 0, 0);
        f32x4 a2 = __builtin_amdgcn_mfma_f32_16x16x32_bf16(kc2, qf, zf, 0, 0, 0);
        f32x4 a3 = __builtin_amdgcn_mfma_f32_16x16x32_bf16(kc3, qf, zf, 0, 0, 0);
        LOADK(kc, 1)
        unsigned short* pw = &p_scr[0][w][prow + quad*4];
        PAM_DO(pw, 0, a0) PAM_DO(pw, 1, a1) PAM_DO(pw, 2, a2) PAM_DO(pw, 3, a3)
    }
    // i=1: scores(1) -> s_prev regs
    sp0 = __builtin_amdgcn_mfma_f32_16x16x32_bf16(kc0, qf, zf, 0, 0, 0);
    sp1 = __builtin_amdgcn_mfma_f32_16x16x32_bf16(kc1, qf, zf, 0, 0, 0);
    sp2 = __builtin_amdgcn_mfma_f32_16x16x32_bf16(kc2, qf, zf, 0, 0, 0);
    sp3 = __builtin_amdgcn_mfma_f32_16x16x32_bf16(kc3, qf, zf, 0, 0, 0);
    LOADK(kc, 2)

    // ---------------- main loop: i = 2..63 ----------------
    // scores(i) || exp/pack/write P(i-1) || PV(i-2)
#pragma unroll 2
    for (int i = 2; i < NT; ++i) {
        // scores(i) — K(i) in kc regs
        const f32x4 t0 = __builtin_amdgcn_mfma_f32_16x16x32_bf16(kc0, qf, zf, 0, 0, 0);
        const f32x4 t1 = __builtin_amdgcn_mfma_f32_16x16x32_bf16(kc1, qf, zf, 0, 0, 0);
        const f32x4 t2 = __builtin_amdgcn_mfma_f32_16x16x32_bf16(kc2, qf, zf, 0, 0, 0);
        const f32x4 t3 = __builtin_amdgcn_mfma_f32_16x16x32_bf16(kc3, qf, zf, 0, 0, 0);

        // ds_read P(i-2) from buf[i&1] (written in iter i-1; latency covered below)
        const unsigned short* pr = &p_scr[i & 1][w][prow + quad*8];
        const short8 a0 = *(const short8*)pr;          // m 0..31
        const short8 a1 = *(const short8*)(pr + 32);   // m 32..63

        // prefetch K(i+1) (i=63 reads one tile past featk8 — mapped ws memory,
        // values discarded)
        LOADK(kn, i + 1)

        // exp/pack/write P(i-1) -> buf[(i+1)&1]  (s_prev from a full iter ago)
        {
            unsigned short* pw = &p_scr[(i + 1) & 1][w][prow + quad*4];
            PAM_DO(pw, 0, sp0) PAM_DO(pw, 1, sp1) PAM_DO(pw, 2, sp2) PAM_DO(pw, 3, sp3)
        }

        // PV(i-2) with vv = V(i-2); l rides the MFMA pipe via ones-B
        acc0 = __builtin_amdgcn_mfma_f32_16x16x32_bf16(a0, vv0, acc0, 0, 0, 0);
        acc0 = __builtin_amdgcn_mfma_f32_16x16x32_bf16(a1, vv1, acc0, 0, 0, 0);
        acc1 = __builtin_amdgcn_mfma_f32_16x16x32_bf16(a0, vv2, acc1, 0, 0, 0);
        acc1 = __builtin_amdgcn_mfma_f32_16x16x32_bf16(a1, vv3, acc1, 0, 0, 0);
        accL = __builtin_amdgcn_mfma_f32_16x16x32_bf16(a0, onesb, accL, 0, 0, 0);
        accL = __builtin_amdgcn_mfma_f32_16x16x32_bf16(a1, onesb, accL, 0, 0, 0);

        // rotate: vv <- V(i-1), load vn = V(i) (used at iter i+2)
        vv0 = vn0; vv1 = vn1; vv2 = vn2; vv3 = vn3;
        LOADV(vn, i)
        kc0 = kn0; kc1 = kn1; kc2 = kn2; kc3 = kn3;
        sp0 = t0; sp1 = t1; sp2 = t2; sp3 = t3;
    }

    // ---------------- epilogue ----------------
    {   // E1: PV(62) + write P(63)
        const unsigned short* pr = &p_scr[0][w][prow + quad*8];   // P(62): buf[64&1]
        const short8 a0 = *(const short8*)pr;
        const short8 a1 = *(const short8*)(pr + 32);
        unsigned short* pw = &p_scr[1][w][prow + quad*4];         // P(63) -> buf[63&1]
        PAM_DO(pw, 0, sp0) PAM_DO(pw, 1, sp1) PAM_DO(pw, 2, sp2) PAM_DO(pw, 3, sp3)
        acc0 = __builtin_amdgcn_mfma_f32_16x16x32_bf16(a0, vv0, acc0, 0, 0, 0);
        acc0 = __builtin_amdgcn_mfma_f32_16x16x32_bf16(a1, vv1, acc0, 0, 0, 0);
        acc1 = __builtin_amdgcn_mfma_f32_16x16x32_bf16(a0, vv2, acc1, 0, 0, 0);
        acc1 = __builtin_amdgcn_mfma_f32_16x16x32_bf16(a1, vv3, acc1, 0, 0, 0);
        accL = __builtin_amdgcn_mfma_f32_16x16x32_bf16(a0, onesb, accL, 0, 0, 0);
        accL = __builtin_amdgcn_mfma_f32_16x16x32_bf16(a1, onesb, accL, 0, 0, 0);
        vv0 = vn0; vv1 = vn1; vv2 = vn2; vv3 = vn3;               // V(63)
    }
    {   // E2: PV(63)
        const unsigned short* pr = &p_scr[1][w][prow + quad*8];
        const short8 a0 = *(const short8*)pr;
        const short8 a1 = *(const short8*)(pr + 32);
        acc0 = __builtin_amdgcn_mfma_f32_16x16x32_bf16(a0, vv0, acc0, 0, 0, 0);
        acc0 = __builtin_amdgcn_mfma_f32_16x16x32_bf16(a1, vv1, acc0, 0, 0, 0);
        acc1 = __builtin_amdgcn_mfma_f32_16x16x32_bf16(a0, vv2, acc1, 0, 0, 0);
        acc1 = __builtin_amdgcn_mfma_f32_16x16x32_bf16(a1, vv3, acc1, 0, 0, 0);
        accL = __builtin_amdgcn_mfma_f32_16x16x32_bf16(a0, onesb, accL, 0, 0, 0);
        accL = __builtin_amdgcn_mfma_f32_16x16x32_bf16(a1, onesb, accL, 0, 0, 0);
    }
#undef PAM_DO
#undef LOADK
#undef LOADV

    // ---- epilogue: accL[r] = l[q = quad*4+r] — exactly acc0/acc1's q-mapping.
    const float alpha = alpha_p[0];
    const float c0 = alpha / (accL[0] + 1e-30f);
    const float c1 = alpha / (accL[1] + 1e-30f);
    const float c2 = alpha / (accL[2] + 1e-30f);
    const float c3 = alpha / (accL[3] + 1e-30f);
#pragma unroll
    for (int cb = 0; cb < 2; ++cb) {
        const int ch = chh*32 + cb*16 + row16;
        const size_t base = (size_t)(b*CH + ch)*NSP + n0w + quad*4;
        const float4 f = *(const float4*)&fm[base];
        const f32x4 a = cb ? acc1 : acc0;
        float4 o;
        o.x = fmaf(c0, a[0], f.x);
        o.y = fmaf(c1, a[1], f.y);
        o.z = fmaf(c2, a[2], f.z);
        o.w = fmaf(c3, a[3], f.w);
        *(float4*)&out[base] = o;
    }
}

// ---------------- launcher ----------------
extern "C" void kernel_launch(void* const* d_in, const int* in_sizes, int n_in,
                              void* d_out, int out_size, void* d_ws, size_t ws_size,
                              hipStream_t stream)
{
    const float* map1  = (const float*)d_in[0];
    const float* map2  = (const float*)d_in[1];
    const float* fm    = (const float*)d_in[2];
    const float* wb    = (const float*)d_in[3];
    const float* bb    = (const float*)d_in[4];
    const float* wc    = (const float*)d_in[5];
    const float* bc    = (const float*)d_in[6];
    const float* wd    = (const float*)d_in[7];
    const float* bd    = (const float*)d_in[8];
    const float* alpha = (const float*)d_in[9];
    float* out = (float*)d_out;

    // ws: featq8 bf16 [4][4096][8] 256KB | featk8 256KB | featdf frag 2MB
    unsigned short* featq8 = (unsigned short*)d_ws;
    unsigned short* featk8 = featq8 + (size_t)BATCH*NSP*8;
    unsigned short* featdf = featk8 + (size_t)BATCH*NSP*8;

    proj_kernel<<<dim3(NSP/64, 2, BATCH), 256, 0, stream>>>(
        map1, map2, fm, wb, bb, wc, bc, wd, bd, featq8, featk8, featdf);
    attn_kernel<<<dim3(NSP/64, 2, BATCH), 256, 0, stream>>>(
        featq8, featk8, featdf, fm, alpha, out);
}

// Round 10
// 118.359 us; speedup vs baseline: 1.0410x; 1.0410x over previous
//
#include <hip/hip_runtime.h>
#include <hip/hip_bf16.h>
#include <math.h>

// PAM fused attention, round 10: de-duplicated exp path.
// Block = 4 waves: wave (qsub, khalf) = 16 queries x ALL 64 channels x half the
// keys. Each (q,key) exp/score computed exactly once (R7-R9 duplicated x2 via
// the channel split). Key-split is INTRA-block (R4 lesson: cross-block key
// chunks break V-stream lockstep; intra-block pairs stay in step and combine
// through LDS). Layouts byte-identical to R7-R9. B=4, Cm=6, C=64, N=4096.

#define BATCH 4
#define CMAP  6
#define CH    64
#define NSP   4096
#define TN    64         // keys per tile
#define NTH   32         // tiles per wave (2048 keys per key-half)
#define PSTR  72         // p_scr row stride (bf16)

typedef __attribute__((ext_vector_type(8))) short short8;
typedef __attribute__((ext_vector_type(4))) float f32x4;

#if __has_builtin(__builtin_amdgcn_exp2f)
#define EXP2(x) __builtin_amdgcn_exp2f(x)
#else
#define EXP2(x) exp2f(x)
#endif

__device__ __forceinline__ unsigned f2bf(float f) {      // RNE f32->bf16 bits
    unsigned u = __float_as_uint(f);
    return (u + 0x7fffu + ((u >> 16) & 1u)) >> 16;
}

#define INVLN2 1.44269504088896f
#define SHIFT_BF16 0xC238u   /* bf16(-46.0): fixed softmax shift (exact, cancels) */
#define ONE_BF16   0x3F80u

// V fragment layout: featdf[b][ht(128)][cb(4)][512]
//   half-tile ht = 32 keys; cb = 16-channel block.
//   elem ((quad*16 + r)*8 + j) = V[m=ht*32+quad*8+j][ch=cb*16+r]
//   -> MFMA lane l=(quad*16+row16) loads its 16B at frag_base + l*8 elems.

// ---------------- kernel 1: projections + V fragment transpose ----------------
// (unchanged from R7-R9, verified) grid (NSP/64, 2, BATCH), block 256.
__global__ void proj_kernel(const float* __restrict__ map1, const float* __restrict__ map2,
                            const float* __restrict__ fm,
                            const float* __restrict__ wb, const float* __restrict__ bb,
                            const float* __restrict__ wc, const float* __restrict__ bc,
                            const float* __restrict__ wd, const float* __restrict__ bd,
                            unsigned short* __restrict__ featq8,
                            unsigned short* __restrict__ featk8,
                            unsigned short* __restrict__ featdf)
{
    __shared__ unsigned short vfrag[2048];   // [ht(2)][cb_local(2)][512] = 4KB

    const int b    = blockIdx.z;
    const int half = blockIdx.y;
    const int lane = threadIdx.x & 63;
    const int og   = threadIdx.x >> 6;
    const int n    = blockIdx.x * 64 + lane;

    const int ht = lane >> 5;
    const int mm = lane & 31;
    const int q4 = mm >> 3, jj = mm & 7;
    const int cb_local = og >> 1;
    float vals[CH];
#pragma unroll
    for (int c = 0; c < CH; ++c)
        vals[c] = fm[(size_t)(b*CH + c)*NSP + n];
#pragma unroll
    for (int oi = 0; oi < 8; ++oi) {
        const int o = half*32 + og*8 + oi;
        float a = bd[o];
#pragma unroll
        for (int c = 0; c < CH; ++c)
            a = fmaf(vals[c], wd[o*CH + c], a);
        const int r = (og & 1)*8 + oi;
        vfrag[(ht*2 + cb_local)*512 + (q4*16 + r)*8 + jj] = (unsigned short)f2bf(a);
    }

    if (half == 0 && og == 0) {
        float v1[CMAP], v2[CMAP];
#pragma unroll
        for (int c = 0; c < CMAP; ++c) {
            v1[c] = map1[(size_t)(b*CMAP + c)*NSP + n];
            v2[c] = map2[(size_t)(b*CMAP + c)*NSP + n];
        }
        unsigned qv[CMAP], kv[CMAP];
#pragma unroll
        for (int o = 0; o < CMAP; ++o) {
            float a1 = bb[o], a2 = bc[o];
#pragma unroll
            for (int c = 0; c < CMAP; ++c) {
                a1 = fmaf(v1[c], wb[o*CMAP + c], a1);
                a2 = fmaf(v2[c], wc[o*CMAP + c], a2);
            }
            qv[o] = f2bf(a1 * INVLN2);
            kv[o] = f2bf(a2);
        }
        uint4 qw, kw;
        qw.x = qv[0] | (qv[1] << 16);
        qw.y = qv[2] | (qv[3] << 16);
        qw.z = qv[4] | (qv[5] << 16);
        qw.w = SHIFT_BF16;
        kw.x = kv[0] | (kv[1] << 16);
        kw.y = kv[2] | (kv[3] << 16);
        kw.z = kv[4] | (kv[5] << 16);
        kw.w = ONE_BF16;
        *(uint4*)&featq8[(size_t)(b*NSP + n)*8] = qw;
        *(uint4*)&featk8[(size_t)(b*NSP + n)*8] = kw;
    }

    __syncthreads();

    {
        const int tt = threadIdx.x;
        const uint4 d = *(const uint4*)&vfrag[tt*8];
        const int ht2 = tt >> 7, inner = tt & 127;
        const size_t off = (((size_t)(b*128 + blockIdx.x*2 + ht2)*4) + half*2)*512
                         + (size_t)inner*8;
        *(uint4*)&featdf[off] = d;
    }
}

// ---------------- kernel 2: attention, intra-block key-split -----------------
// grid (NSP/32=128, BATCH) = 512 blocks -> 2 blocks/CU, 8 waves/CU.
// Wave (qsub, khalf): 16 queries x 64 channels x 2048 keys. 3-stage pipeline.
__global__ __launch_bounds__(256, 2)
void attn_kernel(const unsigned short* __restrict__ featq8,
                 const unsigned short* __restrict__ featk8,
                 const unsigned short* __restrict__ featdf,
                 const float* __restrict__ fm, const float* __restrict__ alpha_p,
                 float* __restrict__ out)
{
    __shared__ unsigned short p_scr[2][4][16*PSTR];  // [buf][wave][q][m] wave-private
    __shared__ float cmb[2][64][21];                 // key-half partial exchange

    const int b    = blockIdx.y;
    const int t    = threadIdx.x;
    const int lane = t & 63, w = t >> 6;
    const int row16 = lane & 15, quad = lane >> 4;
    const int qsub  = w >> 1;                      // 16-query sub-tile
    const int khalf = w & 1;                       // key half
    const int n0w  = blockIdx.x * 32 + qsub * 16;  // this wave's 16 queries
    const int m0   = khalf * (NSP/2);              // this wave's 2048 keys

    // Q B-frag: B[k=quad*8+j][q=row16]; quads 1-3 zero (kills unguarded-K garbage)
    short8 qf = {0,0,0,0,0,0,0,0};
    if (quad == 0)
        qf = *(const short8*)&featq8[(size_t)(b*NSP + n0w + row16)*8];

    // ones B-frag: accL = P x 1 -> softmax denominator, same D q-mapping as acc
    const short8 onesb = {(short)ONE_BF16,(short)ONE_BF16,(short)ONE_BF16,(short)ONE_BF16,
                          (short)ONE_BF16,(short)ONE_BF16,(short)ONE_BF16,(short)ONE_BF16};

    // K A-frag stream (this key half)
    const unsigned short* kbase = featk8 + ((size_t)(b*NSP + m0) + row16)*8 + quad*8;
    // V fragment stream: coalesced, lane*16B within each 1KB frag; all 4 cb
    const unsigned short* vfb = featdf + ((size_t)b*128*4)*512 + lane*8;
    const int hb = khalf * 64;                     // half-tile base for this key half

    const f32x4 zf = {0.f,0.f,0.f,0.f};
    f32x4 acc[4] = {zf, zf, zf, zf};
    f32x4 accL = zf;
    const int prow = row16 * PSTR;

#define PAM_DO(pwp, mb, sv)                                                     \
    {                                                                           \
        const float p0 = EXP2(sv[0]), p1 = EXP2(sv[1]);                         \
        const float p2 = EXP2(sv[2]), p3 = EXP2(sv[3]);                         \
        uint2 pp;                                                               \
        pp.x = __builtin_amdgcn_perm(__float_as_uint(p1), __float_as_uint(p0), 0x07060302u); \
        pp.y = __builtin_amdgcn_perm(__float_as_uint(p3), __float_as_uint(p2), 0x07060302u); \
        *(uint2*)((pwp) + (mb)*16) = pp;                                        \
    }

#define LOADK(dst, mt)                                                          \
    dst##0 = *(const short8*)(kbase + ((mt)*TN +  0)*8);                        \
    dst##1 = *(const short8*)(kbase + ((mt)*TN + 16)*8);                        \
    dst##2 = *(const short8*)(kbase + ((mt)*TN + 32)*8);                        \
    dst##3 = *(const short8*)(kbase + ((mt)*TN + 48)*8);

    // V for tile vt: half-tiles hb+vt*2, hb+vt*2+1; cb 0..3 (8 x b128)
#define LOADV(dst, vt)                                                          \
    dst##0 = *(const short8*)(vfb + (size_t)((hb + (vt)*2 + 0)*4 + 0)*512);     \
    dst##1 = *(const short8*)(vfb + (size_t)((hb + (vt)*2 + 1)*4 + 0)*512);     \
    dst##2 = *(const short8*)(vfb + (size_t)((hb + (vt)*2 + 0)*4 + 1)*512);     \
    dst##3 = *(const short8*)(vfb + (size_t)((hb + (vt)*2 + 1)*4 + 1)*512);     \
    dst##4 = *(const short8*)(vfb + (size_t)((hb + (vt)*2 + 0)*4 + 2)*512);     \
    dst##5 = *(const short8*)(vfb + (size_t)((hb + (vt)*2 + 1)*4 + 2)*512);     \
    dst##6 = *(const short8*)(vfb + (size_t)((hb + (vt)*2 + 0)*4 + 3)*512);     \
    dst##7 = *(const short8*)(vfb + (size_t)((hb + (vt)*2 + 1)*4 + 3)*512);

#define PV(a0_, a1_, vset)                                                      \
    acc[0] = __builtin_amdgcn_mfma_f32_16x16x32_bf16(a0_, vset##0, acc[0], 0, 0, 0); \
    acc[0] = __builtin_amdgcn_mfma_f32_16x16x32_bf16(a1_, vset##1, acc[0], 0, 0, 0); \
    acc[1] = __builtin_amdgcn_mfma_f32_16x16x32_bf16(a0_, vset##2, acc[1], 0, 0, 0); \
    acc[1] = __builtin_amdgcn_mfma_f32_16x16x32_bf16(a1_, vset##3, acc[1], 0, 0, 0); \
    acc[2] = __builtin_amdgcn_mfma_f32_16x16x32_bf16(a0_, vset##4, acc[2], 0, 0, 0); \
    acc[2] = __builtin_amdgcn_mfma_f32_16x16x32_bf16(a1_, vset##5, acc[2], 0, 0, 0); \
    acc[3] = __builtin_amdgcn_mfma_f32_16x16x32_bf16(a0_, vset##6, acc[3], 0, 0, 0); \
    acc[3] = __builtin_amdgcn_mfma_f32_16x16x32_bf16(a1_, vset##7, acc[3], 0, 0, 0); \
    accL   = __builtin_amdgcn_mfma_f32_16x16x32_bf16(a0_, onesb, accL, 0, 0, 0);     \
    accL   = __builtin_amdgcn_mfma_f32_16x16x32_bf16(a1_, onesb, accL, 0, 0, 0);

    short8 kc0, kc1, kc2, kc3, kn0, kn1, kn2, kn3;
    short8 vv0, vv1, vv2, vv3, vv4, vv5, vv6, vv7;
    short8 vn0, vn1, vn2, vn3, vn4, vn5, vn6, vn7;
    f32x4 sp0, sp1, sp2, sp3;

    // ---------------- prologue ----------------
    LOADK(kc, 0)
    LOADV(vv, 0)            // V(0)
    LOADV(vn, 1)            // V(1)

    {   // i=0: scores(0) -> pack P(0) into buf[0]
        f32x4 a0 = __builtin_amdgcn_mfma_f32_16x16x32_bf16(kc0, qf, zf, 0, 0, 0);
        f32x4 a1 = __builtin_amdgcn_mfma_f32_16x16x32_bf16(kc1, qf, zf, 0, 0, 0);
        f32x4 a2 = __builtin_amdgcn_mfma_f32_16x16x32_bf16(kc2, qf, zf, 0, 0, 0);
        f32x4 a3 = __builtin_amdgcn_mfma_f32_16x16x32_bf16(kc3, qf, zf, 0, 0, 0);
        LOADK(kc, 1)
        unsigned short* pw = &p_scr[0][w][prow + quad*4];
        PAM_DO(pw, 0, a0) PAM_DO(pw, 1, a1) PAM_DO(pw, 2, a2) PAM_DO(pw, 3, a3)
    }
    // i=1: scores(1) -> s_prev regs
    sp0 = __builtin_amdgcn_mfma_f32_16x16x32_bf16(kc0, qf, zf, 0, 0, 0);
    sp1 = __builtin_amdgcn_mfma_f32_16x16x32_bf16(kc1, qf, zf, 0, 0, 0);
    sp2 = __builtin_amdgcn_mfma_f32_16x16x32_bf16(kc2, qf, zf, 0, 0, 0);
    sp3 = __builtin_amdgcn_mfma_f32_16x16x32_bf16(kc3, qf, zf, 0, 0, 0);
    LOADK(kc, 2)

    // ---------------- main loop: i = 2..31 ----------------
    // scores(i) || exp/pack/write P(i-1) || PV(i-2)
#pragma unroll 2
    for (int i = 2; i < NTH; ++i) {
        const f32x4 t0 = __builtin_amdgcn_mfma_f32_16x16x32_bf16(kc0, qf, zf, 0, 0, 0);
        const f32x4 t1 = __builtin_amdgcn_mfma_f32_16x16x32_bf16(kc1, qf, zf, 0, 0, 0);
        const f32x4 t2 = __builtin_amdgcn_mfma_f32_16x16x32_bf16(kc2, qf, zf, 0, 0, 0);
        const f32x4 t3 = __builtin_amdgcn_mfma_f32_16x16x32_bf16(kc3, qf, zf, 0, 0, 0);

        // ds_read P(i-2) from buf[i&1] (written iter i-1)
        const unsigned short* pr = &p_scr[i & 1][w][prow + quad*8];
        const short8 a0 = *(const short8*)pr;          // m 0..31
        const short8 a1 = *(const short8*)(pr + 32);   // m 32..63

        // prefetch K(i+1) (i=31 reads past this half -> mapped ws, discarded)
        LOADK(kn, i + 1)

        // exp/pack/write P(i-1) -> buf[(i+1)&1]
        {
            unsigned short* pw = &p_scr[(i + 1) & 1][w][prow + quad*4];
            PAM_DO(pw, 0, sp0) PAM_DO(pw, 1, sp1) PAM_DO(pw, 2, sp2) PAM_DO(pw, 3, sp3)
        }

        // PV(i-2), all 4 cb + l on the MFMA pipe
        PV(a0, a1, vv)

        // rotate V; load V(i) (used at iter i+2)
        vv0 = vn0; vv1 = vn1; vv2 = vn2; vv3 = vn3;
        vv4 = vn4; vv5 = vn5; vv6 = vn6; vv7 = vn7;
        LOADV(vn, i)
        kc0 = kn0; kc1 = kn1; kc2 = kn2; kc3 = kn3;
        sp0 = t0; sp1 = t1; sp2 = t2; sp3 = t3;
    }

    // ---------------- epilogue ----------------
    {   // E1: PV(30) + write P(31)
        const unsigned short* pr = &p_scr[0][w][prow + quad*8];   // P(30): buf[32&1]
        const short8 a0 = *(const short8*)pr;
        const short8 a1 = *(const short8*)(pr + 32);
        unsigned short* pw = &p_scr[1][w][prow + quad*4];         // P(31) -> buf[1]
        PAM_DO(pw, 0, sp0) PAM_DO(pw, 1, sp1) PAM_DO(pw, 2, sp2) PAM_DO(pw, 3, sp3)
        PV(a0, a1, vv)
        vv0 = vn0; vv1 = vn1; vv2 = vn2; vv3 = vn3;               // V(31)
        vv4 = vn4; vv5 = vn5; vv6 = vn6; vv7 = vn7;
    }
    {   // E2: PV(31)
        const unsigned short* pr = &p_scr[1][w][prow + quad*8];
        const short8 a0 = *(const short8*)pr;
        const short8 a1 = *(const short8*)(pr + 32);
        PV(a0, a1, vv)
    }
#undef PAM_DO
#undef LOADK
#undef LOADV
#undef PV

    // ---------------- combine key halves + epilogue ----------------
    // khalf==1 waves publish partials; khalf==0 waves reduce and write out.
    if (khalf == 1) {
        float* c = cmb[qsub][lane];
#pragma unroll
        for (int cb = 0; cb < 4; ++cb)
            *(float4*)&c[cb*4] = (float4){acc[cb][0], acc[cb][1], acc[cb][2], acc[cb][3]};
        *(float4*)&c[16] = (float4){accL[0], accL[1], accL[2], accL[3]};
    }
    __syncthreads();
    if (khalf == 0) {
        const float* c = cmb[qsub][lane];
        const float4 lo = *(const float4*)&c[16];
        const float alpha = alpha_p[0];
        const float c0 = alpha / (accL[0] + lo.x + 1e-30f);
        const float c1 = alpha / (accL[1] + lo.y + 1e-30f);
        const float c2 = alpha / (accL[2] + lo.z + 1e-30f);
        const float c3 = alpha / (accL[3] + 1e-30f + lo.w);
#pragma unroll
        for (int cb = 0; cb < 4; ++cb) {
            const float4 po = *(const float4*)&c[cb*4];
            const int ch = cb*16 + row16;
            const size_t base = (size_t)(b*CH + ch)*NSP + n0w + quad*4;
            const float4 f = *(const float4*)&fm[base];
            float4 o;
            o.x = fmaf(c0, acc[cb][0] + po.x, f.x);
            o.y = fmaf(c1, acc[cb][1] + po.y, f.y);
            o.z = fmaf(c2, acc[cb][2] + po.z, f.z);
            o.w = fmaf(c3, acc[cb][3] + po.w, f.w);
            *(float4*)&out[base] = o;
        }
    }
}

// ---------------- launcher ----------------
extern "C" void kernel_launch(void* const* d_in, const int* in_sizes, int n_in,
                              void* d_out, int out_size, void* d_ws, size_t ws_size,
                              hipStream_t stream)
{
    const float* map1  = (const float*)d_in[0];
    const float* map2  = (const float*)d_in[1];
    const float* fm    = (const float*)d_in[2];
    const float* wb    = (const float*)d_in[3];
    const float* bb    = (const float*)d_in[4];
    const float* wc    = (const float*)d_in[5];
    const float* bc    = (const float*)d_in[6];
    const float* wd    = (const float*)d_in[7];
    const float* bd    = (const float*)d_in[8];
    const float* alpha = (const float*)d_in[9];
    float* out = (float*)d_out;

    // ws: featq8 bf16 [4][4096][8] 256KB | featk8 256KB | featdf frag 2MB
    unsigned short* featq8 = (unsigned short*)d_ws;
    unsigned short* featk8 = featq8 + (size_t)BATCH*NSP*8;
    unsigned short* featdf = featk8 + (size_t)BATCH*NSP*8;

    proj_kernel<<<dim3(NSP/64, 2, BATCH), 256, 0, stream>>>(
        map1, map2, fm, wb, bb, wc, bc, wd, bd, featq8, featk8, featdf);
    attn_kernel<<<dim3(NSP/32, BATCH), 256, 0, stream>>>(
        featq8, featk8, featdf, fm, alpha, out);
}